// Round 7
// baseline (114.840 us; speedup 1.0000x reference)
//
#include <hip/hip_runtime.h>

#define B_ 32
#define T_ 512
#define D_ 256
#define P_ 8
#define BT (B_*T_)
#define EPS 0.08f

typedef float f4 __attribute__((ext_vector_type(4)));
typedef __attribute__((ext_vector_type(8))) short short8;

__device__ inline unsigned short f2bf(float f) {
  unsigned u = __builtin_bit_cast(unsigned, f);
  u += 0x7fffu + ((u >> 16) & 1u);   // RNE
  return (unsigned short)(u >> 16);
}

// ---------------- kernel 0: W1 -> bf16 bits (same [e][d] layout) ----------------
__global__ void k_prep(const float* __restrict__ W1, unsigned short* __restrict__ W1b) {
  int i = blockIdx.x * 256 + threadIdx.x;
  W1b[i] = f2bf(W1[i]);
}

// ---------------- kernel 1: MFMA GEMM1 + exact fp32 GEMM2 + top2-argmax --------
// 512 blocks x 256 thr. Block = 32 rows. Wave w: e-strip [w*64, w*64+64).
// NO global atomics: margin flag goes to a plain per-row array.
__global__ __launch_bounds__(256) void k_dur(
    const float* __restrict__ x, const unsigned short* __restrict__ W1b,
    const float* __restrict__ b1, const float* __restrict__ W2,
    const float* __restrict__ b2, int* __restrict__ dur,
    int* __restrict__ flagm)
{
  __shared__ float lp[4][32][P_];   // per-wave logit partials, 4 KB

  const int tid = threadIdx.x;
  const int lane = tid & 63;
  const int w   = tid >> 6;
  const int row0 = blockIdx.x * 32;
  const int n0  = w * 64;
  const int l15 = lane & 15, lk = lane >> 4;

  f4 acc[2][4] = {};

  #pragma unroll
  for (int ks = 0; ks < 8; ++ks) {
    // B fragments: col = e = n0+nt*16+l15, k = ks*32 + lk*8 + j
    short8 bf[4];
    #pragma unroll
    for (int nt = 0; nt < 4; ++nt)
      bf[nt] = *(const short8*)(W1b + (size_t)(n0 + nt * 16 + l15) * D_ + ks * 32 + lk * 8);
    // A fragments: row = row0+mt*16+l15, same k; fp32->bf16 RNE in-register
    short8 af[2];
    #pragma unroll
    for (int mt = 0; mt < 2; ++mt) {
      const float* ap = x + (size_t)(row0 + mt * 16 + l15) * D_ + ks * 32 + lk * 8;
      f4 lo = *(const f4*)ap, hi = *(const f4*)(ap + 4);
      short8 t;
      t[0] = (short)f2bf(lo[0]); t[1] = (short)f2bf(lo[1]);
      t[2] = (short)f2bf(lo[2]); t[3] = (short)f2bf(lo[3]);
      t[4] = (short)f2bf(hi[0]); t[5] = (short)f2bf(hi[1]);
      t[6] = (short)f2bf(hi[2]); t[7] = (short)f2bf(hi[3]);
      af[mt] = t;
    }
    #pragma unroll
    for (int mt = 0; mt < 2; ++mt)
      #pragma unroll
      for (int nt = 0; nt < 4; ++nt)
        acc[mt][nt] = __builtin_amdgcn_mfma_f32_16x16x32_bf16(af[mt], bf[nt], acc[mt][nt], 0, 0, 0);
  }

  // ---- epilogue: h = relu(acc + b1); exact fp32 GEMM2 partials over lane's e's
  float b1v[4], w2v[4][P_];
  #pragma unroll
  for (int nt = 0; nt < 4; ++nt) {
    int e = n0 + nt * 16 + l15;
    b1v[nt] = b1[e];
    #pragma unroll
    for (int p = 0; p < P_; ++p) w2v[nt][p] = W2[p * D_ + e];
  }

  #pragma unroll
  for (int mt = 0; mt < 2; ++mt) {
    float vv[32];   // vv[r*8+p]
    #pragma unroll
    for (int i = 0; i < 32; ++i) vv[i] = 0.f;
    #pragma unroll
    for (int nt = 0; nt < 4; ++nt)
      #pragma unroll
      for (int r = 0; r < 4; ++r) {
        float h = fmaxf(acc[mt][nt][r] + b1v[nt], 0.f);
        #pragma unroll
        for (int p = 0; p < P_; ++p) vv[r * 8 + p] = fmaf(h, w2v[nt][p], vv[r * 8 + p]);
      }

    // split-butterfly over the 16-lane e-group: 32 values fold to 2 per lane
    #pragma unroll
    for (int k = 0; k < 4; ++k) {
      const int s = 1 << k;
      const int half = 16 >> k;
      const bool up = (lane & s) != 0;
      #pragma unroll
      for (int i = 0; i < half; ++i) {
        float a = vv[i], b = vv[i + half];
        float send = up ? a : b;
        float recv = __shfl_xor(send, s, 64);
        vv[i] = (up ? b : a) + recv;
      }
    }
    // lane owns value index v = i + 16*b0 + 8*b1 + 4*b2 + 2*b3 (bk = lane bit k)
    {
      int b0 = lane & 1, b1_ = (lane >> 1) & 1, b2_ = (lane >> 2) & 1, b3 = (lane >> 3) & 1;
      #pragma unroll
      for (int i = 0; i < 2; ++i) {
        int v = i + 16 * b0 + 8 * b1_ + 4 * b2_ + 2 * b3;
        lp[w][mt * 16 + lk * 4 + (v >> 3)][v & 7] = vv[i];
      }
    }
  }
  __syncthreads();

  // ---- final: sum 4 wave-partials, top-2 argmax per row, flag narrow margins
  {
    int row = tid >> 3, p = tid & 7;
    float top = b2[p] + lp[0][row][p] + lp[1][row][p] + lp[2][row][p] + lp[3][row][p];
    int   tp  = p;
    float sec = -__builtin_inff();
    #pragma unroll
    for (int s = 1; s < 8; s <<= 1) {
      float ov = __shfl_xor(top, s, 64);
      int   op = __shfl_xor(tp,  s, 64);
      float os = __shfl_xor(sec, s, 64);
      bool take = (ov > top) || (ov == top && op < tp);   // np argmax: first max wins
      float loser = take ? top : ov;
      top = take ? ov : top;
      tp  = take ? op : tp;
      sec = fmaxf(loser, fmaxf(sec, os));
    }
    if ((tid & 7) == 0) {
      dur[row0 + row] = tp;
      flagm[row0 + row] = (top - sec < EPS) ? 1 : 0;   // plain store, NO atomic
    }
  }
}

// ---------------- kernel 2: exact fp32 recompute for flagged rows --------------
// 256 blocks x 256 thr; block b OWNS rows [64b, 64b+64): local ballot-compact,
// then 8 rows per iteration. No cross-block communication, no atomics.
__global__ __launch_bounds__(256) void k_fix(
    const float* __restrict__ x, const float* __restrict__ W1,
    const float* __restrict__ b1, const float* __restrict__ W2,
    const float* __restrict__ b2, int* __restrict__ dur,
    const int* __restrict__ flagm)
{
  __shared__ int   list[64];
  __shared__ int   nloc;
  __shared__ int   ridx[8];
  __shared__ float xs[8][D_];
  __shared__ float hs[8][D_];
  __shared__ float ls[8][P_];
  const int t = threadIdx.x;
  const int row0 = blockIdx.x * 64;

  // ---- wave-0 ballot compaction of this block's 64 rows
  if (t < 64) {
    int f = flagm[row0 + t];
    unsigned long long m = __ballot(f != 0);
    int pre = __popcll(m & ((1ull << t) - 1ull));
    if (f) list[pre] = row0 + t;
    if (t == 0) nloc = __popcll(m);
  }
  __syncthreads();
  const int n = nloc;

  for (int base = 0; base < n; base += 8) {
    if (t < 8 && base + t < n) ridx[t] = list[base + t];
    __syncthreads();
    {
      int j = t >> 5, c = (t & 31) * 8;
      if (base + j < n) {
        const float* p = x + (size_t)ridx[j] * D_ + c;
        f4 a = *(const f4*)p, b = *(const f4*)(p + 4);
        *(f4*)&xs[j][c] = a; *(f4*)&xs[j][c + 4] = b;
      }
    }
    __syncthreads();

    {   // GEMM1: thread e computes h[r][e] for 8 rows (8-way ILP chains)
      int e = t;
      float ar[8];
      #pragma unroll
      for (int r = 0; r < 8; ++r) ar[r] = b1[e];
      for (int kt = 0; kt < 8; ++kt) {
        float wreg[32];
        #pragma unroll
        for (int q = 0; q < 8; ++q)
          *(f4*)&wreg[q * 4] = *(const f4*)(W1 + (size_t)e * D_ + kt * 32 + q * 4);
        #pragma unroll
        for (int r = 0; r < 8; ++r) {
          float lo = 0.f;
          #pragma unroll
          for (int d = 0; d < 32; ++d) lo = fmaf(xs[r][kt * 32 + d], wreg[d], lo);
          ar[r] += lo;
        }
      }
      #pragma unroll
      for (int r = 0; r < 8; ++r) hs[r][e] = fmaxf(ar[r], 0.f);
    }
    __syncthreads();

    {   // GEMM2: p = t>>5, sub = t&31; 64 FMA + 5-step shfl reduce
      int p = t >> 5, sub = t & 31;
      float part[8];
      #pragma unroll
      for (int r = 0; r < 8; ++r) part[r] = 0.f;
      #pragma unroll
      for (int j = 0; j < 8; ++j) {
        int e = sub * 8 + j;
        float w2 = W2[p * D_ + e];
        #pragma unroll
        for (int r = 0; r < 8; ++r) part[r] = fmaf(hs[r][e], w2, part[r]);
      }
      #pragma unroll
      for (int s = 1; s < 32; s <<= 1)
        #pragma unroll
        for (int r = 0; r < 8; ++r) part[r] += __shfl_xor(part[r], s, 64);
      if (sub == 0)
        #pragma unroll
        for (int r = 0; r < 8; ++r) ls[r][p] = part[r] + b2[p];
    }
    __syncthreads();

    if (t < 64) {
      int r = t >> 3, p = t & 7;
      float top = ls[r][p]; int tp = p;
      #pragma unroll
      for (int s = 1; s < 8; s <<= 1) {
        float ov = __shfl_xor(top, s, 64);
        int   op = __shfl_xor(tp,  s, 64);
        bool take = (ov > top) || (ov == top && op < tp);
        top = take ? ov : top;
        tp  = take ? op : tp;
      }
      if ((t & 7) == 0 && base + r < n) dur[ridx[r]] = tp;
    }
    __syncthreads();
  }
}

// ---------------- kernel 3: per-batch shfl scan + scatter src ----------------
__global__ void k_scan(const int* __restrict__ dur, int* __restrict__ src, int mel) {
  __shared__ int wsum[8];
  int t = threadIdx.x, b = blockIdx.x;
  int lane = t & 63, wave = t >> 6;
  int d = dur[b * T_ + t];
  int v = d;
  #pragma unroll
  for (int s = 1; s < 64; s <<= 1) {
    int u = __shfl_up(v, s, 64);
    if (lane >= s) v += u;
  }
  if (lane == 63) wsum[wave] = v;
  __syncthreads();
  if (t == 0) {
    int run = 0;
    #pragma unroll
    for (int i = 0; i < 8; ++i) { run += wsum[i]; wsum[i] = run; }
  }
  __syncthreads();
  int cs = v + (wave ? wsum[wave - 1] : 0);
  int start = cs - d;
  int total = wsum[7];
  for (int m = start; m < cs; ++m) src[b * mel + m] = t;
  for (int m = total + t; m < mel; m += T_) src[b * mel + m] = -1;
}

// ---------------- kernel 4: gather/expand ----------------
__global__ __launch_bounds__(256) void k_gather(
    const float* __restrict__ x, const int* __restrict__ src,
    float* __restrict__ out, int mel)
{
  int lane = threadIdx.x & 63;
  int wave = threadIdx.x >> 6;
  int m = blockIdx.x * 4 + wave;
  int b = blockIdx.y;
  if (m >= mel) return;
  int s = src[b * mel + m];
  f4 val = {0.f, 0.f, 0.f, 0.f};
  if (s >= 0) val = *(const f4*)(x + ((size_t)b * T_ + s) * D_ + lane * 4);
  *(f4*)(out + ((size_t)b * mel + m) * D_ + lane * 4) = val;
}

extern "C" void kernel_launch(void* const* d_in, const int* in_sizes, int n_in,
                              void* d_out, int out_size, void* d_ws, size_t ws_size,
                              hipStream_t stream) {
  const float* x  = (const float*)d_in[0];
  const float* W1 = (const float*)d_in[1];
  const float* b1 = (const float*)d_in[2];
  const float* W2 = (const float*)d_in[3];
  const float* b2 = (const float*)d_in[4];
  float* out = (float*)d_out;

  int mel = out_size / (B_ * D_);   // 3584

  char* wp = (char*)d_ws;           // 704 KB total (proven envelope)
  unsigned short* W1b = (unsigned short*)wp;  wp += D_ * D_ * sizeof(short);  // 128 KB
  int* flagm = (int*)wp;                      wp += BT * sizeof(int);         // 64 KB
  int* dur   = (int*)wp;                      wp += BT * sizeof(int);         // 64 KB
  int* src   = (int*)wp;                                                      // 448 KB

  k_prep<<<D_ * D_ / 256, 256, 0, stream>>>(W1, W1b);
  k_dur<<<BT / 32, 256, 0, stream>>>(x, W1b, b1, W2, b2, dur, flagm);
  k_fix<<<BT / 64, 256, 0, stream>>>(x, W1, b1, W2, b2, dur, flagm);
  k_scan<<<B_, T_, 0, stream>>>(dur, src, mel);
  k_gather<<<dim3((mel + 3) / 4, B_), 256, 0, stream>>>(x, src, out, mel);
}

// Round 8
// 110.729 us; speedup vs baseline: 1.0371x; 1.0371x over previous
//
#include <hip/hip_runtime.h>

#define B_ 32
#define T_ 512
#define D_ 256
#define P_ 8
#define BT (B_*T_)
#define EPS 0.08f

typedef float f4 __attribute__((ext_vector_type(4)));
typedef __attribute__((ext_vector_type(8))) short short8;

__device__ inline unsigned short f2bf(float f) {
  unsigned u = __builtin_bit_cast(unsigned, f);
  u += 0x7fffu + ((u >> 16) & 1u);   // RNE
  return (unsigned short)(u >> 16);
}

// ---- kernel 0: W1 -> bf16 bits (same layout) AND fp32 transpose w1t[d][e] ----
__global__ void k_prep(const float* __restrict__ W1, unsigned short* __restrict__ W1b,
                       float* __restrict__ w1t) {
  int e = blockIdx.x;        // 256
  int d = threadIdx.x;       // 256
  float w = W1[e * D_ + d];  // coalesced read
  W1b[e * D_ + d] = f2bf(w);
  w1t[d * D_ + e] = w;       // scattered write (one-time, 256 KB)
}

// ---------------- kernel 1: MFMA GEMM1 + exact fp32 GEMM2 + top2-argmax --------
// 512 blocks x 256 thr. Block = 32 rows. Wave w: e-strip [w*64, w*64+64).
__global__ __launch_bounds__(256) void k_dur(
    const float* __restrict__ x, const unsigned short* __restrict__ W1b,
    const float* __restrict__ b1, const float* __restrict__ W2,
    const float* __restrict__ b2, int* __restrict__ dur,
    int* __restrict__ flagm)
{
  __shared__ float lp[4][32][P_];   // per-wave logit partials, 4 KB

  const int tid = threadIdx.x;
  const int lane = tid & 63;
  const int w   = tid >> 6;
  const int row0 = blockIdx.x * 32;
  const int n0  = w * 64;
  const int l15 = lane & 15, lk = lane >> 4;

  f4 acc[2][4] = {};

  #pragma unroll
  for (int ks = 0; ks < 8; ++ks) {
    short8 bf[4];
    #pragma unroll
    for (int nt = 0; nt < 4; ++nt)
      bf[nt] = *(const short8*)(W1b + (size_t)(n0 + nt * 16 + l15) * D_ + ks * 32 + lk * 8);
    short8 af[2];
    #pragma unroll
    for (int mt = 0; mt < 2; ++mt) {
      const float* ap = x + (size_t)(row0 + mt * 16 + l15) * D_ + ks * 32 + lk * 8;
      f4 lo = *(const f4*)ap, hi = *(const f4*)(ap + 4);
      short8 t;
      t[0] = (short)f2bf(lo[0]); t[1] = (short)f2bf(lo[1]);
      t[2] = (short)f2bf(lo[2]); t[3] = (short)f2bf(lo[3]);
      t[4] = (short)f2bf(hi[0]); t[5] = (short)f2bf(hi[1]);
      t[6] = (short)f2bf(hi[2]); t[7] = (short)f2bf(hi[3]);
      af[mt] = t;
    }
    #pragma unroll
    for (int mt = 0; mt < 2; ++mt)
      #pragma unroll
      for (int nt = 0; nt < 4; ++nt)
        acc[mt][nt] = __builtin_amdgcn_mfma_f32_16x16x32_bf16(af[mt], bf[nt], acc[mt][nt], 0, 0, 0);
  }

  float b1v[4], w2v[4][P_];
  #pragma unroll
  for (int nt = 0; nt < 4; ++nt) {
    int e = n0 + nt * 16 + l15;
    b1v[nt] = b1[e];
    #pragma unroll
    for (int p = 0; p < P_; ++p) w2v[nt][p] = W2[p * D_ + e];
  }

  #pragma unroll
  for (int mt = 0; mt < 2; ++mt) {
    float vv[32];   // vv[r*8+p]
    #pragma unroll
    for (int i = 0; i < 32; ++i) vv[i] = 0.f;
    #pragma unroll
    for (int nt = 0; nt < 4; ++nt)
      #pragma unroll
      for (int r = 0; r < 4; ++r) {
        float h = fmaxf(acc[mt][nt][r] + b1v[nt], 0.f);
        #pragma unroll
        for (int p = 0; p < P_; ++p) vv[r * 8 + p] = fmaf(h, w2v[nt][p], vv[r * 8 + p]);
      }

    #pragma unroll
    for (int k = 0; k < 4; ++k) {
      const int s = 1 << k;
      const int half = 16 >> k;
      const bool up = (lane & s) != 0;
      #pragma unroll
      for (int i = 0; i < half; ++i) {
        float a = vv[i], b = vv[i + half];
        float send = up ? a : b;
        float recv = __shfl_xor(send, s, 64);
        vv[i] = (up ? b : a) + recv;
      }
    }
    {
      int b0 = lane & 1, b1_ = (lane >> 1) & 1, b2_ = (lane >> 2) & 1, b3 = (lane >> 3) & 1;
      #pragma unroll
      for (int i = 0; i < 2; ++i) {
        int v = i + 16 * b0 + 8 * b1_ + 4 * b2_ + 2 * b3;
        lp[w][mt * 16 + lk * 4 + (v >> 3)][v & 7] = vv[i];
      }
    }
  }
  __syncthreads();

  {
    int row = tid >> 3, p = tid & 7;
    float top = b2[p] + lp[0][row][p] + lp[1][row][p] + lp[2][row][p] + lp[3][row][p];
    int   tp  = p;
    float sec = -__builtin_inff();
    #pragma unroll
    for (int s = 1; s < 8; s <<= 1) {
      float ov = __shfl_xor(top, s, 64);
      int   op = __shfl_xor(tp,  s, 64);
      float os = __shfl_xor(sec, s, 64);
      bool take = (ov > top) || (ov == top && op < tp);   // np argmax: first max wins
      float loser = take ? top : ov;
      top = take ? ov : top;
      tp  = take ? op : tp;
      sec = fmaxf(loser, fmaxf(sec, os));
    }
    if ((tid & 7) == 0) {
      dur[row0 + row] = tp;
      flagm[row0 + row] = (top - sec < EPS) ? 1 : 0;
    }
  }
}

// ---------------- kernel 2: exact fp32 recompute for flagged rows --------------
// 256 blocks x 256 thr; block b OWNS rows [64b, 64b+64): ballot-compact, 8/iter.
// W1 read COALESCED via w1t (lane = e). Values/order bit-identical to R7 pass.
__global__ __launch_bounds__(256) void k_fix(
    const float* __restrict__ x, const float* __restrict__ w1t,
    const float* __restrict__ b1, const float* __restrict__ W2,
    const float* __restrict__ b2, int* __restrict__ dur,
    const int* __restrict__ flagm)
{
  __shared__ int   list[64];
  __shared__ int   nloc;
  __shared__ int   ridx[8];
  __shared__ float xs[8][D_];
  __shared__ float hs[8][D_];
  __shared__ float ls[8][P_];
  const int t = threadIdx.x;
  const int row0 = blockIdx.x * 64;

  if (t < 64) {
    int f = flagm[row0 + t];
    unsigned long long m = __ballot(f != 0);
    int pre = __popcll(m & ((1ull << t) - 1ull));
    if (f) list[pre] = row0 + t;
    if (t == 0) nloc = __popcll(m);
  }
  __syncthreads();
  const int n = nloc;

  for (int base = 0; base < n; base += 8) {
    if (t < 8 && base + t < n) ridx[t] = list[base + t];
    __syncthreads();
    {
      int j = t >> 5, c = (t & 31) * 8;
      if (base + j < n) {
        const float* p = x + (size_t)ridx[j] * D_ + c;
        f4 a = *(const f4*)p, b = *(const f4*)(p + 4);
        *(f4*)&xs[j][c] = a; *(f4*)&xs[j][c + 4] = b;
      }
    }
    __syncthreads();

    {   // GEMM1: thread e computes h[r][e] for 8 rows; W1 via w1t, coalesced
      int e = t;
      float ar[8];
      #pragma unroll
      for (int r = 0; r < 8; ++r) ar[r] = b1[e];
      for (int kt = 0; kt < 8; ++kt) {
        float wreg[32];
        #pragma unroll
        for (int dd = 0; dd < 32; ++dd)
          wreg[dd] = w1t[(size_t)(kt * 32 + dd) * D_ + e];   // lane-coalesced
        #pragma unroll
        for (int r = 0; r < 8; ++r) {
          float lo = 0.f;
          #pragma unroll
          for (int d = 0; d < 32; ++d) lo = fmaf(xs[r][kt * 32 + d], wreg[d], lo);
          ar[r] += lo;
        }
      }
      #pragma unroll
      for (int r = 0; r < 8; ++r) hs[r][e] = fmaxf(ar[r], 0.f);
    }
    __syncthreads();

    {   // GEMM2: p = t>>5, sub = t&31; 64 FMA + 5-step shfl reduce
      int p = t >> 5, sub = t & 31;
      float part[8];
      #pragma unroll
      for (int r = 0; r < 8; ++r) part[r] = 0.f;
      #pragma unroll
      for (int j = 0; j < 8; ++j) {
        int e = sub * 8 + j;
        float w2 = W2[p * D_ + e];
        #pragma unroll
        for (int r = 0; r < 8; ++r) part[r] = fmaf(hs[r][e], w2, part[r]);
      }
      #pragma unroll
      for (int s = 1; s < 32; s <<= 1)
        #pragma unroll
        for (int r = 0; r < 8; ++r) part[r] += __shfl_xor(part[r], s, 64);
      if (sub == 0)
        #pragma unroll
        for (int r = 0; r < 8; ++r) ls[r][p] = part[r] + b2[p];
    }
    __syncthreads();

    if (t < 64) {
      int r = t >> 3, p = t & 7;
      float top = ls[r][p]; int tp = p;
      #pragma unroll
      for (int s = 1; s < 8; s <<= 1) {
        float ov = __shfl_xor(top, s, 64);
        int   op = __shfl_xor(tp,  s, 64);
        bool take = (ov > top) || (ov == top && op < tp);
        top = take ? ov : top;
        tp  = take ? op : tp;
      }
      if ((t & 7) == 0 && base + r < n) dur[ridx[r]] = tp;
    }
    __syncthreads();
  }
}

// ---------------- kernel 3: per-batch shfl scan + scatter src ----------------
__global__ void k_scan(const int* __restrict__ dur, int* __restrict__ src, int mel) {
  __shared__ int wsum[8];
  int t = threadIdx.x, b = blockIdx.x;
  int lane = t & 63, wave = t >> 6;
  int d = dur[b * T_ + t];
  int v = d;
  #pragma unroll
  for (int s = 1; s < 64; s <<= 1) {
    int u = __shfl_up(v, s, 64);
    if (lane >= s) v += u;
  }
  if (lane == 63) wsum[wave] = v;
  __syncthreads();
  if (t == 0) {
    int run = 0;
    #pragma unroll
    for (int i = 0; i < 8; ++i) { run += wsum[i]; wsum[i] = run; }
  }
  __syncthreads();
  int cs = v + (wave ? wsum[wave - 1] : 0);
  int start = cs - d;
  int total = wsum[7];
  for (int m = start; m < cs; ++m) src[b * mel + m] = t;
  for (int m = total + t; m < mel; m += T_) src[b * mel + m] = -1;
}

// ---------------- kernel 4: gather/expand ----------------
__global__ __launch_bounds__(256) void k_gather(
    const float* __restrict__ x, const int* __restrict__ src,
    float* __restrict__ out, int mel)
{
  int lane = threadIdx.x & 63;
  int wave = threadIdx.x >> 6;
  int m = blockIdx.x * 4 + wave;
  int b = blockIdx.y;
  if (m >= mel) return;
  int s = src[b * mel + m];
  f4 val = {0.f, 0.f, 0.f, 0.f};
  if (s >= 0) val = *(const f4*)(x + ((size_t)b * T_ + s) * D_ + lane * 4);
  *(f4*)(out + ((size_t)b * mel + m) * D_ + lane * 4) = val;
}

extern "C" void kernel_launch(void* const* d_in, const int* in_sizes, int n_in,
                              void* d_out, int out_size, void* d_ws, size_t ws_size,
                              hipStream_t stream) {
  const float* x  = (const float*)d_in[0];
  const float* W1 = (const float*)d_in[1];
  const float* b1 = (const float*)d_in[2];
  const float* W2 = (const float*)d_in[3];
  const float* b2 = (const float*)d_in[4];
  float* out = (float*)d_out;

  int mel = out_size / (B_ * D_);   // 3584

  char* wp = (char*)d_ws;           // 704 KB total (proven envelope)
  unsigned short* W1b = (unsigned short*)wp;  wp += D_ * D_ * sizeof(short);  // 128 KB
  int* flagm = (int*)wp;                      wp += BT * sizeof(int);         // 64 KB
  int* dur   = (int*)wp;                      wp += BT * sizeof(int);         // 64 KB
  int* src   = (int*)wp;                                                      // 448 KB
  float* w1t = (float*)src;  // ALIAS: w1t (256 KB) lives in src's region; dead
                             // before k_scan writes src. No cross-call state.

  k_prep<<<D_, D_, 0, stream>>>(W1, W1b, w1t);
  k_dur<<<BT / 32, 256, 0, stream>>>(x, W1b, b1, W2, b2, dur, flagm);
  k_fix<<<BT / 64, 256, 0, stream>>>(x, w1t, b1, W2, b2, dur, flagm);
  k_scan<<<B_, T_, 0, stream>>>(dur, src, mel);
  k_gather<<<dim3((mel + 3) / 4, B_), 256, 0, stream>>>(x, src, out, mel);
}